// Round 8
// baseline (283.085 us; speedup 1.0000x reference)
//
#include <hip/hip_runtime.h>

typedef __bf16 bf16x8 __attribute__((ext_vector_type(8)));
typedef float  f32x4  __attribute__((ext_vector_type(4)));
typedef float  f32x2  __attribute__((ext_vector_type(2)));

#define NCH 24
#define CP  26        // padded channel stride (floats) -> conflict-free, 8B-aligned pairs
#define HW 128
#define IMG (HW*HW)
#define CHIMG (NCH*IMG)
#define SXP 20        // staged x (16 + 2*2 halo)
#define SYP 8         // staged y (4 + 2*2 halo)
#define S1XP 18       // step-1 intermediate x
#define S1YP 6        // step-1 intermediate y
#define S1N (S1XP*S1YP)   // 108

// d_ws layout: [ping state: 4*CHIMG floats][w1 frags][w2 frags][b2 frags]
#define PW1_OFF ((size_t)(4*CHIMG)*4)
#define PW2_OFF (PW1_OFF + 12*64*8*2)
#define PB2_OFF (PW2_OFF + 4*64*8*2)

// One-time weight packing into MFMA A-fragment layout (bias-1 trick in t=3 slot).
// mfma_f32_16x16x32_bf16: A[row=l%16][k=8*(l/16)+j], B[k][col=l%16], D[row=4*(l/16)+r][col=l%16]
__global__ void nca_pack_weights(const float* __restrict__ w1, const float* __restrict__ b1,
                                 const float* __restrict__ w2, const float* __restrict__ b2,
                                 char* __restrict__ ws)
{
    short* pw1 = (short*)(ws + PW1_OFF);
    short* pw2 = (short*)(ws + PW2_OFF);
    float* pb2 = (float*)(ws + PB2_OFF);
    const int tid = threadIdx.x;
    for (int idx = tid; idx < 12*64*8; idx += 256) {
        int j  = idx & 7;
        int ll = (idx >> 3) & 63;
        int fs = idx >> 9;                  // m*3+s
        int m  = fs / 3, s = fs - 3*m;
        int row = m*16 + (ll & 15);         // h
        int kp  = 32*s + 8*(ll >> 4) + j;   // k' = 4c+t
        int c = kp >> 2, tt = kp & 3;
        float v;
        if (tt < 3) v = w1[row*72 + 3*c + tt];
        else        v = (c == 0) ? b1[row] : 0.f;
        pw1[idx] = (short)__builtin_bit_cast(unsigned short, (__bf16)v);
    }
    for (int idx = tid; idx < 4*64*8; idx += 256) {
        int j  = idx & 7;
        int ll = (idx >> 3) & 63;
        int fs = idx >> 9;                  // m2*2+s2
        int m2 = fs >> 1, s2 = fs & 1;
        int row = m2*16 + (ll & 15);        // o
        int h   = 32*s2 + 8*(ll >> 4) + j;
        float v = (row < 24) ? w2[row*64 + h] : 0.f;
        pw2[idx] = (short)__builtin_bit_cast(unsigned short, (__bf16)v);
    }
    for (int idx = tid; idx < 2*64*4; idx += 256) {
        int r  = idx & 3;
        int ll = (idx >> 2) & 63;
        int m2 = idx >> 8;
        int o  = m2*16 + 4*(ll >> 4) + r;
        pb2[idx] = (o < 24) ? b2[o] : 0.f;
    }
}

// One NCA micro-step for one pixel-slot: perception (packed-f32 channel-pair
// math from a pixel-major LDS tile) -> GEMM1 (w1 frags from LDS) -> relu/
// transpose (per-wave Hb) -> GEMM2 (w2 frags from global/L1).
// Returns delta accumulators (without b2) in d0 (ch 0..15 as 4g+r) and d1 (16..23).
template<int XP>
__device__ __forceinline__ void nca_mlp(
    const float* __restrict__ stsrc, int sy, int sx,
    int l, int px, int g, int wv, short (*Hb)[16][72],
    const short* __restrict__ w1l, const short* __restrict__ pw2,
    f32x4& d0, f32x4& d1)
{
    const float* base = stsrc + ((sy-1)*XP + (sx-1))*CP + 2*g;
    bf16x8 pf[3];
    #pragma unroll
    for (int s = 0; s < 3; ++s) {
        #define LDV(dy,dx) (*(const f32x2*)(base + ((dy)*XP + (dx))*CP + 8*s))
        f32x2 v00=LDV(0,0), v01=LDV(0,1), v02=LDV(0,2);
        f32x2 v10=LDV(1,0), v11=LDV(1,1), v12=LDV(1,2);
        f32x2 v20=LDV(2,0), v21=LDV(2,1), v22=LDV(2,2);
        #undef LDV
        // packed f32 (v_pk_add/fma_f32): both channels per op
        f32x2 gx = (v02 - v00 + 2.f*(v12 - v10) + (v22 - v20)) * 0.125f;
        f32x2 gy = (v20 - v00 + 2.f*(v21 - v01) + (v22 - v02)) * 0.125f;
        pf[s][0] = (__bf16)v11.x;
        pf[s][1] = (__bf16)gx.x;
        pf[s][2] = (__bf16)gy.x;
        pf[s][3] = (__bf16)((s == 0 && g == 0) ? 1.f : 0.f);   // bias-1 slot (c==0)
        pf[s][4] = (__bf16)v11.y;
        pf[s][5] = (__bf16)gx.y;
        pf[s][6] = (__bf16)gy.y;
        pf[s][7] = (__bf16)0.f;
    }

    // GEMM1: H^T = w1' x p~^T  (A-frags from LDS: one base reg + imm offsets)
    f32x4 acc1[4] = {};
    #pragma unroll
    for (int m = 0; m < 4; ++m) {
        #pragma unroll
        for (int s = 0; s < 3; ++s) {
            bf16x8 a = *(const bf16x8*)&w1l[((m*3 + s)*64 + l)*8];
            acc1[m] = __builtin_amdgcn_mfma_f32_16x16x32_bf16(a, pf[s], acc1[m], 0, 0, 0);
        }
    }

    // relu + per-wave transpose: 4 shorts (rows h0..h0+3) per 8B write
    #pragma unroll
    for (int m = 0; m < 4; ++m) {
        unsigned int b0 = __builtin_bit_cast(unsigned short, (__bf16)fmaxf(acc1[m][0], 0.f));
        unsigned int b1_ = __builtin_bit_cast(unsigned short, (__bf16)fmaxf(acc1[m][1], 0.f));
        unsigned int b2_ = __builtin_bit_cast(unsigned short, (__bf16)fmaxf(acc1[m][2], 0.f));
        unsigned int b3 = __builtin_bit_cast(unsigned short, (__bf16)fmaxf(acc1[m][3], 0.f));
        uint2 w; w.x = b0 | (b1_ << 16); w.y = b2_ | (b3 << 16);
        *(uint2*)&Hb[wv][px][m*16 + 4*g] = w;      // 8B-aligned
    }
    // same-wave write->read: compiler inserts lgkmcnt wait, no barrier needed

    // GEMM2: delta^T = w2 x relu(H)^T
    f32x4 acc2[2] = {};
    #pragma unroll
    for (int s2 = 0; s2 < 2; ++s2) {
        bf16x8 hv = *(const bf16x8*)&Hb[wv][px][8*g + 32*s2];
        #pragma unroll
        for (int m2 = 0; m2 < 2; ++m2) {
            bf16x8 a2 = *(const bf16x8*)&pw2[((m2*2 + s2)*64 + l)*8];
            acc2[m2] = __builtin_amdgcn_mfma_f32_16x16x32_bf16(a2, hv, acc2[m2], 0, 0, 0);
        }
    }
    d0 = acc2[0];
    d1 = acc2[1];
}

// Fused 2-step NCA (temporal blocking, halo=2), pixel-major LDS tiles,
// w1 fragments cached in LDS, packed-f32 VALU math.
__global__ __launch_bounds__(256, 4) void nca_step2(
    const float* __restrict__ src, float* __restrict__ dst,
    const char* __restrict__ wsp, const float* __restrict__ masks, int step0)
{
    __shared__ __align__(16) float st_in[SYP*SXP*CP];   // 16640 B, [y][x][c]
    __shared__ __align__(16) float st1[S1YP*S1XP*CP];   // 11232 B
    __shared__ __align__(16) short Hb[4][16][72];       //  9216 B
    __shared__ __align__(16) short w1l[12*64*8];        //  3072 B... wait: 12*64*8*2 = 12288? no: shorts

    const short* __restrict__ pw2 = (const short*)(wsp + PW2_OFF);
    const float* __restrict__ pb2 = (const float*)(wsp + PB2_OFF);

    const int tid = threadIdx.x;
    const int wv  = tid >> 6;
    const int l   = tid & 63;
    const int px  = l & 15;
    const int g   = l >> 4;

    // XCD-contiguous tile mapping: XCD k (bid%8) owns a contiguous half-batch
    // slab -> ping-pong state stays resident in that XCD's L2.
    const int bid = blockIdx.x;
    const int t   = (bid & 7) * 128 + (bid >> 3);
    const int b   = t >> 8;
    const int y0  = ((t >> 3) & 31) * 4;
    const int x0  = (t & 7) * 16;

    // ---- copy w1 fragments into LDS (3 KB... actually 12*64*8 shorts = 12 KB) ----
    {
        const uint4* s4 = (const uint4*)(wsp + PW1_OFF);
        uint4* d4 = (uint4*)w1l;
        for (int i = tid; i < 12*64*8*2/16; i += 256) d4[i] = s4[i];
    }

    // ---- stage 8x20 tile, pixel-major (zero "SAME" pad) ----
    const float* sb = src + b * CHIMG;
    for (int idx = tid; idx < NCH*SYP*SXP; idx += 256) {
        int xx = idx % SXP;
        int tt = idx / SXP;
        int yy = tt % SYP;
        int c  = tt / SYP;
        int gy = y0 + yy - 2;
        int gx = x0 + xx - 2;
        float v = 0.f;
        if ((unsigned)gy < (unsigned)HW && (unsigned)gx < (unsigned)HW)
            v = sb[c*IMG + gy*HW + gx];
        st_in[(yy*SXP + xx)*CP + c] = v;
    }
    __syncthreads();

    const float* mask1 = masks + ((size_t)step0*4 + b)*IMG;
    const float* mask2 = masks + ((size_t)(step0+1)*4 + b)*IMG;
    f32x4 b2v0 = *(const f32x4*)&pb2[(0*64 + l)*4];
    f32x4 b2v1 = *(const f32x4*)&pb2[(1*64 + l)*4];
    const f32x2 b2p0 = {b2v0[0], b2v0[1]}, b2p1 = {b2v0[2], b2v0[3]};
    const f32x2 b2p2 = {b2v1[0], b2v1[1]}, b2p3 = {b2v1[2], b2v1[3]};

    // ============ STEP A: 108 px (6x18) in 7 slots of 16 ============
    for (int itg = 0; itg < 2; ++itg) {
        const int slot = itg*4 + wv;
        if (slot*16 >= S1N) break;                 // slot 7 idle
        const int q  = slot*16 + px;
        const bool lane_valid = (q < S1N);
        const int qq = lane_valid ? q : 0;
        const int r1 = qq / S1XP;
        const int c1 = qq - r1*S1XP;

        f32x4 d0, d1;
        nca_mlp<SXP>(st_in, r1+1, c1+1, l, px, g, wv, Hb, w1l, pw2, d0, d1);

        // epilogue into st1 (zero out-of-image px), packed f32
        const int gy = y0 + r1 - 1;
        const int gx = x0 + c1 - 1;
        const bool inimg = (unsigned)gy < (unsigned)HW && (unsigned)gx < (unsigned)HW;
        const int cy = inimg ? gy : 0;
        const int cx = inimg ? gx : 0;
        float mval = mask1[cy*HW + cx];
        float fire = (inimg && mval < 0.5f) ? 1.f : 0.f;
        float keep = inimg ? 1.f : 0.f;
        if (lane_valid) {
            const int pc  = ((r1+1)*SXP + (c1+1))*CP;   // st_in center pixel
            const int pd  = (r1*S1XP + c1)*CP;          // st1 pixel
            f32x2 ra = *(const f32x2*)&st_in[pc + 4*g];
            f32x2 rb = *(const f32x2*)&st_in[pc + 4*g + 2];
            f32x2 t0 = {d0[0], d0[1]}, t1 = {d0[2], d0[3]};
            *(f32x2*)&st1[pd + 4*g]     = (ra + (t0 + b2p0) * fire) * keep;
            *(f32x2*)&st1[pd + 4*g + 2] = (rb + (t1 + b2p1) * fire) * keep;
            if (g < 2) {
                f32x2 rc = *(const f32x2*)&st_in[pc + 16 + 4*g];
                f32x2 rd = *(const f32x2*)&st_in[pc + 16 + 4*g + 2];
                f32x2 t2 = {d1[0], d1[1]}, t3 = {d1[2], d1[3]};
                *(f32x2*)&st1[pd + 16 + 4*g]     = (rc + (t2 + b2p2) * fire) * keep;
                *(f32x2*)&st1[pd + 16 + 4*g + 2] = (rd + (t3 + b2p3) * fire) * keep;
            }
        }
    }
    __syncthreads();   // all step-A writes visible before step-B reads

    // ============ STEP B: 4x16 core ============
    {
        f32x4 d0, d1;
        nca_mlp<S1XP>(st1, wv+1, px+1, l, px, g, wv, Hb, w1l, pw2, d0, d1);

        const int x = x0 + px;
        const int y = y0 + wv;
        float mval = mask2[y*HW + x];
        float fire = (mval < 0.5f) ? 1.f : 0.f;
        const int pc = ((wv+1)*S1XP + (px+1))*CP;
        float* ob = dst + b*CHIMG + y*HW + x;

        f32x2 ra = *(const f32x2*)&st1[pc + 4*g];
        f32x2 rb = *(const f32x2*)&st1[pc + 4*g + 2];
        f32x2 t0 = {d0[0], d0[1]}, t1 = {d0[2], d0[3]};
        f32x2 o0 = ra + (t0 + b2p0) * fire;
        f32x2 o1 = rb + (t1 + b2p1) * fire;
        ob[(4*g + 0)*IMG] = o0.x;
        ob[(4*g + 1)*IMG] = o0.y;
        ob[(4*g + 2)*IMG] = o1.x;
        ob[(4*g + 3)*IMG] = o1.y;
        if (g < 2) {
            f32x2 rc = *(const f32x2*)&st1[pc + 16 + 4*g];
            f32x2 rd = *(const f32x2*)&st1[pc + 16 + 4*g + 2];
            f32x2 t2 = {d1[0], d1[1]}, t3 = {d1[2], d1[3]};
            f32x2 o2 = rc + (t2 + b2p2) * fire;
            f32x2 o3 = rd + (t3 + b2p3) * fire;
            ob[(16 + 4*g + 0)*IMG] = o2.x;
            ob[(16 + 4*g + 1)*IMG] = o2.y;
            ob[(16 + 4*g + 2)*IMG] = o3.x;
            ob[(16 + 4*g + 3)*IMG] = o3.y;
        }
    }
}

extern "C" void kernel_launch(void* const* d_in, const int* in_sizes, int n_in,
                              void* d_out, int out_size, void* d_ws, size_t ws_size,
                              hipStream_t stream) {
    const float* state = (const float*)d_in[0];
    const float* w1    = (const float*)d_in[1];
    const float* b1    = (const float*)d_in[2];
    const float* w2    = (const float*)d_in[3];
    const float* b2    = (const float*)d_in[4];
    const float* masks = (const float*)d_in[5];

    float* out = (float*)d_out;
    float* ws  = (float*)d_ws;
    const char* wsc = (const char*)d_ws;

    nca_pack_weights<<<dim3(1), dim3(256), 0, stream>>>(w1, b1, w2, b2, (char*)d_ws);

    // 16 fused launches, each advancing 2 steps. Launch i: steps 2i, 2i+1.
    for (int i = 0; i < 16; ++i) {
        const float* src = (i == 0) ? state : ((i & 1) ? ws : out);
        float*       dst = (i & 1) ? out : ws;
        nca_step2<<<dim3(1024), dim3(256), 0, stream>>>(src, dst, wsc, masks, 2*i);
    }
}

// Round 9
// 216.235 us; speedup vs baseline: 1.3092x; 1.3092x over previous
//
#include <hip/hip_runtime.h>

typedef __bf16 bf16x8 __attribute__((ext_vector_type(8)));
typedef float  f32x4  __attribute__((ext_vector_type(4)));
typedef float  f32x2  __attribute__((ext_vector_type(2)));

#define NCH 24
#define CP  26        // padded channel stride (floats) -> conflict-free, 8B-aligned pairs
#define HW 128
#define IMG (HW*HW)
#define CHIMG (NCH*IMG)
#define SXP 20        // staged x (16 + 2*2 halo)
#define SYP 8         // staged y (4 + 2*2 halo)
#define S1XP 18       // step-1 intermediate x
#define S1YP 6        // step-1 intermediate y
#define S1N (S1XP*S1YP)   // 108

// d_ws layout: [ping state: 4*CHIMG floats][w1 frags][w2 frags][b2 frags]
#define PW1_OFF ((size_t)(4*CHIMG)*4)
#define PW2_OFF (PW1_OFF + 12*64*8*2)
#define PB2_OFF (PW2_OFF + 4*64*8*2)

// One-time weight packing into MFMA A-fragment layout (bias-1 trick in t=3 slot).
// mfma_f32_16x16x32_bf16: A[row=l%16][k=8*(l/16)+j], B[k][col=l%16], D[row=4*(l/16)+r][col=l%16]
__global__ void nca_pack_weights(const float* __restrict__ w1, const float* __restrict__ b1,
                                 const float* __restrict__ w2, const float* __restrict__ b2,
                                 char* __restrict__ ws)
{
    short* pw1 = (short*)(ws + PW1_OFF);
    short* pw2 = (short*)(ws + PW2_OFF);
    float* pb2 = (float*)(ws + PB2_OFF);
    const int tid = threadIdx.x;
    for (int idx = tid; idx < 12*64*8; idx += 256) {
        int j  = idx & 7;
        int ll = (idx >> 3) & 63;
        int fs = idx >> 9;                  // m*3+s
        int m  = fs / 3, s = fs - 3*m;
        int row = m*16 + (ll & 15);         // h
        int kp  = 32*s + 8*(ll >> 4) + j;   // k' = 4c+t
        int c = kp >> 2, tt = kp & 3;
        float v;
        if (tt < 3) v = w1[row*72 + 3*c + tt];
        else        v = (c == 0) ? b1[row] : 0.f;
        pw1[idx] = (short)__builtin_bit_cast(unsigned short, (__bf16)v);
    }
    for (int idx = tid; idx < 4*64*8; idx += 256) {
        int j  = idx & 7;
        int ll = (idx >> 3) & 63;
        int fs = idx >> 9;                  // m2*2+s2
        int m2 = fs >> 1, s2 = fs & 1;
        int row = m2*16 + (ll & 15);        // o
        int h   = 32*s2 + 8*(ll >> 4) + j;
        float v = (row < 24) ? w2[row*64 + h] : 0.f;
        pw2[idx] = (short)__builtin_bit_cast(unsigned short, (__bf16)v);
    }
    for (int idx = tid; idx < 2*64*4; idx += 256) {
        int r  = idx & 3;
        int ll = (idx >> 2) & 63;
        int m2 = idx >> 8;
        int o  = m2*16 + 4*(ll >> 4) + r;
        pb2[idx] = (o < 24) ? b2[o] : 0.f;
    }
}

// One NCA micro-step for one pixel-slot: perception (packed-f32 channel-pair
// math from a pixel-major LDS tile) -> GEMM1 (w1 frags in VGPRs) -> relu/
// transpose (per-wave Hb) -> GEMM2 (w2 frags from global/L1).
// Returns delta accumulators (without b2) in d0 (ch 0..15 as 4g+r) and d1 (16..23).
template<int XP>
__device__ __forceinline__ void nca_mlp(
    const float* __restrict__ stsrc, int sy, int sx,
    int l, int px, int g, int wv, short (*Hb)[16][72],
    const bf16x8 (&w1r)[12], const short* __restrict__ pw2,
    f32x4& d0, f32x4& d1)
{
    const float* base = stsrc + ((sy-1)*XP + (sx-1))*CP + 2*g;
    bf16x8 pf[3];
    #pragma unroll
    for (int s = 0; s < 3; ++s) {
        #define LDV(dy,dx) (*(const f32x2*)(base + ((dy)*XP + (dx))*CP + 8*s))
        f32x2 v00=LDV(0,0), v01=LDV(0,1), v02=LDV(0,2);
        f32x2 v10=LDV(1,0), v11=LDV(1,1), v12=LDV(1,2);
        f32x2 v20=LDV(2,0), v21=LDV(2,1), v22=LDV(2,2);
        #undef LDV
        // packed f32 (v_pk_add/fma_f32): both channels per op
        f32x2 gx = (v02 - v00 + 2.f*(v12 - v10) + (v22 - v20)) * 0.125f;
        f32x2 gy = (v20 - v00 + 2.f*(v21 - v01) + (v22 - v02)) * 0.125f;
        pf[s][0] = (__bf16)v11.x;
        pf[s][1] = (__bf16)gx.x;
        pf[s][2] = (__bf16)gy.x;
        pf[s][3] = (__bf16)((s == 0 && g == 0) ? 1.f : 0.f);   // bias-1 slot (c==0)
        pf[s][4] = (__bf16)v11.y;
        pf[s][5] = (__bf16)gx.y;
        pf[s][6] = (__bf16)gy.y;
        pf[s][7] = (__bf16)0.f;
    }

    // GEMM1: H^T = w1' x p~^T  (A-frags live in VGPRs -- no loads)
    f32x4 acc1[4] = {};
    #pragma unroll
    for (int m = 0; m < 4; ++m) {
        #pragma unroll
        for (int s = 0; s < 3; ++s) {
            acc1[m] = __builtin_amdgcn_mfma_f32_16x16x32_bf16(w1r[m*3 + s], pf[s], acc1[m], 0, 0, 0);
        }
    }

    // relu + per-wave transpose: 4 shorts (rows h0..h0+3) per 8B write
    #pragma unroll
    for (int m = 0; m < 4; ++m) {
        unsigned int b0 = __builtin_bit_cast(unsigned short, (__bf16)fmaxf(acc1[m][0], 0.f));
        unsigned int b1_ = __builtin_bit_cast(unsigned short, (__bf16)fmaxf(acc1[m][1], 0.f));
        unsigned int b2_ = __builtin_bit_cast(unsigned short, (__bf16)fmaxf(acc1[m][2], 0.f));
        unsigned int b3 = __builtin_bit_cast(unsigned short, (__bf16)fmaxf(acc1[m][3], 0.f));
        uint2 w; w.x = b0 | (b1_ << 16); w.y = b2_ | (b3 << 16);
        *(uint2*)&Hb[wv][px][m*16 + 4*g] = w;      // 8B-aligned
    }
    // same-wave write->read: compiler inserts lgkmcnt wait, no barrier needed

    // GEMM2: delta^T = w2 x relu(H)^T
    f32x4 acc2[2] = {};
    #pragma unroll
    for (int s2 = 0; s2 < 2; ++s2) {
        bf16x8 hv = *(const bf16x8*)&Hb[wv][px][8*g + 32*s2];
        #pragma unroll
        for (int m2 = 0; m2 < 2; ++m2) {
            bf16x8 a2 = *(const bf16x8*)&pw2[((m2*2 + s2)*64 + l)*8];
            acc2[m2] = __builtin_amdgcn_mfma_f32_16x16x32_bf16(a2, hv, acc2[m2], 0, 0, 0);
        }
    }
    d0 = acc2[0];
    d1 = acc2[1];
}

// Fused 2-step NCA (temporal blocking, halo=2), pixel-major LDS tiles,
// w1 fragments hoisted to VGPRs, packed-f32 VALU math.
__global__ __launch_bounds__(256, 4) void nca_step2(
    const float* __restrict__ src, float* __restrict__ dst,
    const char* __restrict__ wsp, const float* __restrict__ masks, int step0)
{
    __shared__ __align__(16) float st_in[SYP*SXP*CP];   // 16640 B, [y][x][c]
    __shared__ __align__(16) float st1[S1YP*S1XP*CP];   // 11232 B
    __shared__ __align__(16) short Hb[4][16][72];       //  9216 B

    const short* __restrict__ pw1 = (const short*)(wsp + PW1_OFF);
    const short* __restrict__ pw2 = (const short*)(wsp + PW2_OFF);
    const float* __restrict__ pb2 = (const float*)(wsp + PB2_OFF);

    const int tid = threadIdx.x;
    const int wv  = tid >> 6;
    const int l   = tid & 63;
    const int px  = l & 15;
    const int g   = l >> 4;

    // ---- hoist w1 A-fragments into VGPRs (once per launch, 48 VGPR) ----
    bf16x8 w1r[12];
    #pragma unroll
    for (int i = 0; i < 12; ++i)
        w1r[i] = *(const bf16x8*)&pw1[(i*64 + l)*8];

    // XCD-contiguous tile mapping: XCD k (bid%8) owns a contiguous half-batch
    // slab -> ping-pong state stays resident in that XCD's L2.
    const int bid = blockIdx.x;
    const int t   = (bid & 7) * 128 + (bid >> 3);
    const int b   = t >> 8;
    const int y0  = ((t >> 3) & 31) * 4;
    const int x0  = (t & 7) * 16;

    // ---- stage 8x20 tile, pixel-major (zero "SAME" pad) ----
    const float* sb = src + b * CHIMG;
    for (int idx = tid; idx < NCH*SYP*SXP; idx += 256) {
        int xx = idx % SXP;
        int tt = idx / SXP;
        int yy = tt % SYP;
        int c  = tt / SYP;
        int gy = y0 + yy - 2;
        int gx = x0 + xx - 2;
        float v = 0.f;
        if ((unsigned)gy < (unsigned)HW && (unsigned)gx < (unsigned)HW)
            v = sb[c*IMG + gy*HW + gx];
        st_in[(yy*SXP + xx)*CP + c] = v;
    }
    __syncthreads();

    const float* mask1 = masks + ((size_t)step0*4 + b)*IMG;
    const float* mask2 = masks + ((size_t)(step0+1)*4 + b)*IMG;
    f32x4 b2v0 = *(const f32x4*)&pb2[(0*64 + l)*4];
    f32x4 b2v1 = *(const f32x4*)&pb2[(1*64 + l)*4];
    const f32x2 b2p0 = {b2v0[0], b2v0[1]}, b2p1 = {b2v0[2], b2v0[3]};
    const f32x2 b2p2 = {b2v1[0], b2v1[1]}, b2p3 = {b2v1[2], b2v1[3]};

    // ============ STEP A: 108 px (6x18) in 7 slots of 16 ============
    for (int itg = 0; itg < 2; ++itg) {
        const int slot = itg*4 + wv;
        if (slot*16 >= S1N) break;                 // slot 7 idle
        const int q  = slot*16 + px;
        const bool lane_valid = (q < S1N);
        const int qq = lane_valid ? q : 0;
        const int r1 = qq / S1XP;
        const int c1 = qq - r1*S1XP;

        f32x4 d0, d1;
        nca_mlp<SXP>(st_in, r1+1, c1+1, l, px, g, wv, Hb, w1r, pw2, d0, d1);

        // epilogue into st1 (zero out-of-image px), packed f32
        const int gy = y0 + r1 - 1;
        const int gx = x0 + c1 - 1;
        const bool inimg = (unsigned)gy < (unsigned)HW && (unsigned)gx < (unsigned)HW;
        const int cy = inimg ? gy : 0;
        const int cx = inimg ? gx : 0;
        float mval = mask1[cy*HW + cx];
        float fire = (inimg && mval < 0.5f) ? 1.f : 0.f;
        float keep = inimg ? 1.f : 0.f;
        if (lane_valid) {
            const int pc  = ((r1+1)*SXP + (c1+1))*CP;   // st_in center pixel
            const int pd  = (r1*S1XP + c1)*CP;          // st1 pixel
            f32x2 ra = *(const f32x2*)&st_in[pc + 4*g];
            f32x2 rb = *(const f32x2*)&st_in[pc + 4*g + 2];
            f32x2 t0 = {d0[0], d0[1]}, t1 = {d0[2], d0[3]};
            *(f32x2*)&st1[pd + 4*g]     = (ra + (t0 + b2p0) * fire) * keep;
            *(f32x2*)&st1[pd + 4*g + 2] = (rb + (t1 + b2p1) * fire) * keep;
            if (g < 2) {
                f32x2 rc = *(const f32x2*)&st_in[pc + 16 + 4*g];
                f32x2 rd = *(const f32x2*)&st_in[pc + 16 + 4*g + 2];
                f32x2 t2 = {d1[0], d1[1]}, t3 = {d1[2], d1[3]};
                *(f32x2*)&st1[pd + 16 + 4*g]     = (rc + (t2 + b2p2) * fire) * keep;
                *(f32x2*)&st1[pd + 16 + 4*g + 2] = (rd + (t3 + b2p3) * fire) * keep;
            }
        }
    }
    __syncthreads();   // all step-A writes visible before step-B reads

    // ============ STEP B: 4x16 core ============
    {
        f32x4 d0, d1;
        nca_mlp<S1XP>(st1, wv+1, px+1, l, px, g, wv, Hb, w1r, pw2, d0, d1);

        const int x = x0 + px;
        const int y = y0 + wv;
        float mval = mask2[y*HW + x];
        float fire = (mval < 0.5f) ? 1.f : 0.f;
        const int pc = ((wv+1)*S1XP + (px+1))*CP;
        float* ob = dst + b*CHIMG + y*HW + x;

        f32x2 ra = *(const f32x2*)&st1[pc + 4*g];
        f32x2 rb = *(const f32x2*)&st1[pc + 4*g + 2];
        f32x2 t0 = {d0[0], d0[1]}, t1 = {d0[2], d0[3]};
        f32x2 o0 = ra + (t0 + b2p0) * fire;
        f32x2 o1 = rb + (t1 + b2p1) * fire;
        ob[(4*g + 0)*IMG] = o0.x;
        ob[(4*g + 1)*IMG] = o0.y;
        ob[(4*g + 2)*IMG] = o1.x;
        ob[(4*g + 3)*IMG] = o1.y;
        if (g < 2) {
            f32x2 rc = *(const f32x2*)&st1[pc + 16 + 4*g];
            f32x2 rd = *(const f32x2*)&st1[pc + 16 + 4*g + 2];
            f32x2 t2 = {d1[0], d1[1]}, t3 = {d1[2], d1[3]};
            f32x2 o2 = rc + (t2 + b2p2) * fire;
            f32x2 o3 = rd + (t3 + b2p3) * fire;
            ob[(16 + 4*g + 0)*IMG] = o2.x;
            ob[(16 + 4*g + 1)*IMG] = o2.y;
            ob[(16 + 4*g + 2)*IMG] = o3.x;
            ob[(16 + 4*g + 3)*IMG] = o3.y;
        }
    }
}

extern "C" void kernel_launch(void* const* d_in, const int* in_sizes, int n_in,
                              void* d_out, int out_size, void* d_ws, size_t ws_size,
                              hipStream_t stream) {
    const float* state = (const float*)d_in[0];
    const float* w1    = (const float*)d_in[1];
    const float* b1    = (const float*)d_in[2];
    const float* w2    = (const float*)d_in[3];
    const float* b2    = (const float*)d_in[4];
    const float* masks = (const float*)d_in[5];

    float* out = (float*)d_out;
    float* ws  = (float*)d_ws;
    const char* wsc = (const char*)d_ws;

    nca_pack_weights<<<dim3(1), dim3(256), 0, stream>>>(w1, b1, w2, b2, (char*)d_ws);

    // 16 fused launches, each advancing 2 steps. Launch i: steps 2i, 2i+1.
    for (int i = 0; i < 16; ++i) {
        const float* src = (i == 0) ? state : ((i & 1) ? ws : out);
        float*       dst = (i & 1) ? out : ws;
        nca_step2<<<dim3(1024), dim3(256), 0, stream>>>(src, dst, wsc, masks, 2*i);
    }
}

// Round 10
// 175.266 us; speedup vs baseline: 1.6152x; 1.2338x over previous
//
#include <hip/hip_runtime.h>

typedef __bf16 bf16x8 __attribute__((ext_vector_type(8)));
typedef float  f32x4  __attribute__((ext_vector_type(4)));
typedef float  f32x2  __attribute__((ext_vector_type(2)));

#define NCH 24
#define CP  26        // padded channel stride (floats) -> conflict-free, 8B-aligned pairs
#define HW 128
#define IMG (HW*HW)
#define CHIMG (NCH*IMG)
#define SXP 20        // staged x (16 + 2*2 halo)
#define SYP 12        // staged y (8 + 2*2 halo)
#define S1XP 18       // step-1 intermediate x
#define S1YP 10       // step-1 intermediate y
#define S1N (S1XP*S1YP)   // 180
#define NW 8          // waves per block

// d_ws layout: [ping state: 4*CHIMG floats][w1 frags][w2 frags][b2 frags]
#define PW1_OFF ((size_t)(4*CHIMG)*4)
#define PW2_OFF (PW1_OFF + 12*64*8*2)
#define PB2_OFF (PW2_OFF + 4*64*8*2)

// One-time weight packing into MFMA A-fragment layout (bias-1 trick in t=3 slot).
// mfma_f32_16x16x32_bf16: A[row=l%16][k=8*(l/16)+j], B[k][col=l%16], D[row=4*(l/16)+r][col=l%16]
__global__ void nca_pack_weights(const float* __restrict__ w1, const float* __restrict__ b1,
                                 const float* __restrict__ w2, const float* __restrict__ b2,
                                 char* __restrict__ ws)
{
    short* pw1 = (short*)(ws + PW1_OFF);
    short* pw2 = (short*)(ws + PW2_OFF);
    float* pb2 = (float*)(ws + PB2_OFF);
    const int tid = threadIdx.x;
    for (int idx = tid; idx < 12*64*8; idx += 256) {
        int j  = idx & 7;
        int ll = (idx >> 3) & 63;
        int fs = idx >> 9;                  // m*3+s
        int m  = fs / 3, s = fs - 3*m;
        int row = m*16 + (ll & 15);         // h
        int kp  = 32*s + 8*(ll >> 4) + j;   // k' = 4c+t
        int c = kp >> 2, tt = kp & 3;
        float v;
        if (tt < 3) v = w1[row*72 + 3*c + tt];
        else        v = (c == 0) ? b1[row] : 0.f;
        pw1[idx] = (short)__builtin_bit_cast(unsigned short, (__bf16)v);
    }
    for (int idx = tid; idx < 4*64*8; idx += 256) {
        int j  = idx & 7;
        int ll = (idx >> 3) & 63;
        int fs = idx >> 9;                  // m2*2+s2
        int m2 = fs >> 1, s2 = fs & 1;
        int row = m2*16 + (ll & 15);        // o
        int h   = 32*s2 + 8*(ll >> 4) + j;
        float v = (row < 24) ? w2[row*64 + h] : 0.f;
        pw2[idx] = (short)__builtin_bit_cast(unsigned short, (__bf16)v);
    }
    for (int idx = tid; idx < 2*64*4; idx += 256) {
        int r  = idx & 3;
        int ll = (idx >> 2) & 63;
        int m2 = idx >> 8;
        int o  = m2*16 + 4*(ll >> 4) + r;
        pb2[idx] = (o < 24) ? b2[o] : 0.f;
    }
}

// One NCA micro-step for one pixel-slot: perception (packed-f32 channel-pair
// math from a pixel-major LDS tile) -> GEMM1 (w1 frags in VGPRs) -> relu/
// transpose (per-wave Hb) -> GEMM2 (w2 frags from global/L1).
template<int XP>
__device__ __forceinline__ void nca_mlp(
    const float* __restrict__ stsrc, int sy, int sx,
    int l, int px, int g, short (*hbw)[72],
    const bf16x8 (&w1r)[12], const short* __restrict__ pw2,
    f32x4& d0, f32x4& d1)
{
    const float* base = stsrc + ((sy-1)*XP + (sx-1))*CP + 2*g;
    bf16x8 pf[3];
    #pragma unroll
    for (int s = 0; s < 3; ++s) {
        #define LDV(dy,dx) (*(const f32x2*)(base + ((dy)*XP + (dx))*CP + 8*s))
        f32x2 v00=LDV(0,0), v01=LDV(0,1), v02=LDV(0,2);
        f32x2 v10=LDV(1,0), v11=LDV(1,1), v12=LDV(1,2);
        f32x2 v20=LDV(2,0), v21=LDV(2,1), v22=LDV(2,2);
        #undef LDV
        f32x2 gx = (v02 - v00 + 2.f*(v12 - v10) + (v22 - v20)) * 0.125f;
        f32x2 gy = (v20 - v00 + 2.f*(v21 - v01) + (v22 - v02)) * 0.125f;
        pf[s][0] = (__bf16)v11.x;
        pf[s][1] = (__bf16)gx.x;
        pf[s][2] = (__bf16)gy.x;
        pf[s][3] = (__bf16)((s == 0 && g == 0) ? 1.f : 0.f);   // bias-1 slot (c==0)
        pf[s][4] = (__bf16)v11.y;
        pf[s][5] = (__bf16)gx.y;
        pf[s][6] = (__bf16)gy.y;
        pf[s][7] = (__bf16)0.f;
    }

    // GEMM1: H^T = w1' x p~^T  (A-frags live in VGPRs -- no loads)
    f32x4 acc1[4] = {};
    #pragma unroll
    for (int m = 0; m < 4; ++m) {
        #pragma unroll
        for (int s = 0; s < 3; ++s) {
            acc1[m] = __builtin_amdgcn_mfma_f32_16x16x32_bf16(w1r[m*3 + s], pf[s], acc1[m], 0, 0, 0);
        }
    }

    // relu + per-wave transpose: 4 shorts (rows h0..h0+3) per 8B write
    #pragma unroll
    for (int m = 0; m < 4; ++m) {
        unsigned int b0 = __builtin_bit_cast(unsigned short, (__bf16)fmaxf(acc1[m][0], 0.f));
        unsigned int b1_ = __builtin_bit_cast(unsigned short, (__bf16)fmaxf(acc1[m][1], 0.f));
        unsigned int b2_ = __builtin_bit_cast(unsigned short, (__bf16)fmaxf(acc1[m][2], 0.f));
        unsigned int b3 = __builtin_bit_cast(unsigned short, (__bf16)fmaxf(acc1[m][3], 0.f));
        uint2 w; w.x = b0 | (b1_ << 16); w.y = b2_ | (b3 << 16);
        *(uint2*)&hbw[px][m*16 + 4*g] = w;      // 8B-aligned
    }
    // same-wave write->read: compiler inserts lgkmcnt wait, no barrier needed

    // GEMM2: delta^T = w2 x relu(H)^T
    f32x4 acc2[2] = {};
    #pragma unroll
    for (int s2 = 0; s2 < 2; ++s2) {
        bf16x8 hv = *(const bf16x8*)&hbw[px][8*g + 32*s2];
        #pragma unroll
        for (int m2 = 0; m2 < 2; ++m2) {
            bf16x8 a2 = *(const bf16x8*)&pw2[((m2*2 + s2)*64 + l)*8];
            acc2[m2] = __builtin_amdgcn_mfma_f32_16x16x32_bf16(a2, hv, acc2[m2], 0, 0, 0);
        }
    }
    d0 = acc2[0];
    d1 = acc2[1];
}

// Fused 2-step NCA (temporal blocking, halo=2), 16x8 output tile, 8 waves,
// pixel-major LDS tiles, w1 fragments in VGPRs, strength-reduced staging.
__global__ __launch_bounds__(512, 4) void nca_step2(
    const float* __restrict__ src, float* __restrict__ dst,
    const char* __restrict__ wsp, const float* __restrict__ masks, int step0)
{
    __shared__ __align__(16) float st_in[SYP*SXP*CP];   // 24960 B, [y][x][c]
    __shared__ __align__(16) float st1[S1YP*S1XP*CP];   // 18720 B
    __shared__ __align__(16) short Hb[NW][16][72];      // 18432 B

    const short* __restrict__ pw1 = (const short*)(wsp + PW1_OFF);
    const short* __restrict__ pw2 = (const short*)(wsp + PW2_OFF);
    const float* __restrict__ pb2 = (const float*)(wsp + PB2_OFF);

    const int tid = threadIdx.x;
    const int wv  = tid >> 6;          // 0..7
    const int l   = tid & 63;
    const int px  = l & 15;
    const int g   = l >> 4;

    // ---- hoist w1 A-fragments into VGPRs (once per launch, 48 VGPR) ----
    bf16x8 w1r[12];
    #pragma unroll
    for (int i = 0; i < 12; ++i)
        w1r[i] = *(const bf16x8*)&pw1[(i*64 + l)*8];

    // XCD-contiguous tile mapping: XCD k (bid%8) owns tiles [64k, 64k+64)
    // = half a batch image -> ping-pong state slab stays in that XCD's L2.
    const int bid = blockIdx.x;
    const int t   = (bid & 7) * 64 + (bid >> 3);   // 512 blocks, bijective
    const int b   = t >> 7;                        // batch (128 tiles each)
    const int rem = t & 127;
    const int y0  = (rem >> 3) * 8;                // 16 y-tiles
    const int x0  = (rem & 7) * 16;                // 8 x-tiles

    // ---- stage 12x20 tile, pixel-major, strength-reduced addressing ----
    const float* sb = src + b * CHIMG;
    if (tid < 480) {
        const int c  = tid / 20;          // 0..23
        const int x  = tid - c*20;        // 0..19
        const int gx = x0 + x - 2;
        const bool vx = (unsigned)gx < (unsigned)HW;
        const float* gp = sb + c*IMG + (y0 - 2)*HW + gx;
        float* lp = &st_in[x*CP + c];
        int gy = y0 - 2;
        #pragma unroll
        for (int yy = 0; yy < SYP; ++yy) {
            bool v = vx && ((unsigned)gy < (unsigned)HW);
            lp[yy*SXP*CP] = v ? gp[yy*HW] : 0.f;
            ++gy;
        }
    }
    __syncthreads();

    const float* mask1 = masks + ((size_t)step0*4 + b)*IMG;
    const float* mask2 = masks + ((size_t)(step0+1)*4 + b)*IMG;
    f32x4 b2v0 = *(const f32x4*)&pb2[(0*64 + l)*4];
    f32x4 b2v1 = *(const f32x4*)&pb2[(1*64 + l)*4];
    const f32x2 b2p0 = {b2v0[0], b2v0[1]}, b2p1 = {b2v0[2], b2v0[3]};
    const f32x2 b2p2 = {b2v1[0], b2v1[1]}, b2p3 = {b2v1[2], b2v1[3]};

    // ============ STEP A: 180 px (10x18) in 12 slots of 16 ============
    #pragma unroll
    for (int it = 0; it < 2; ++it) {
        const int slot = it*NW + wv;
        if (slot < 12) {                           // wave-uniform predicate
            const int q  = slot*16 + px;
            const bool lane_valid = (q < S1N);
            const int qq = lane_valid ? q : 0;
            const int r1 = qq / S1XP;
            const int c1 = qq - r1*S1XP;

            f32x4 d0, d1;
            nca_mlp<SXP>(st_in, r1+1, c1+1, l, px, g, Hb[wv], w1r, pw2, d0, d1);

            // epilogue into st1 (zero out-of-image px), packed f32
            const int gy = y0 + r1 - 1;
            const int gx = x0 + c1 - 1;
            const bool inimg = (unsigned)gy < (unsigned)HW && (unsigned)gx < (unsigned)HW;
            const int cy = inimg ? gy : 0;
            const int cx = inimg ? gx : 0;
            float mval = mask1[cy*HW + cx];
            float fire = (inimg && mval < 0.5f) ? 1.f : 0.f;
            float keep = inimg ? 1.f : 0.f;
            if (lane_valid) {
                const int pc = ((r1+1)*SXP + (c1+1))*CP;   // st_in center pixel
                const int pd = (r1*S1XP + c1)*CP;          // st1 pixel
                f32x2 ra = *(const f32x2*)&st_in[pc + 4*g];
                f32x2 rb = *(const f32x2*)&st_in[pc + 4*g + 2];
                f32x2 t0 = {d0[0], d0[1]}, t1 = {d0[2], d0[3]};
                *(f32x2*)&st1[pd + 4*g]     = (ra + (t0 + b2p0) * fire) * keep;
                *(f32x2*)&st1[pd + 4*g + 2] = (rb + (t1 + b2p1) * fire) * keep;
                if (g < 2) {
                    f32x2 rc = *(const f32x2*)&st_in[pc + 16 + 4*g];
                    f32x2 rd = *(const f32x2*)&st_in[pc + 16 + 4*g + 2];
                    f32x2 t2 = {d1[0], d1[1]}, t3 = {d1[2], d1[3]};
                    *(f32x2*)&st1[pd + 16 + 4*g]     = (rc + (t2 + b2p2) * fire) * keep;
                    *(f32x2*)&st1[pd + 16 + 4*g + 2] = (rd + (t3 + b2p3) * fire) * keep;
                }
            }
        }
    }
    __syncthreads();   // all step-A writes visible before step-B reads

    // ============ STEP B: 8x16 core, wave wv = output row y0+wv ============
    {
        f32x4 d0, d1;
        nca_mlp<S1XP>(st1, wv+1, px+1, l, px, g, Hb[wv], w1r, pw2, d0, d1);

        const int x = x0 + px;
        const int y = y0 + wv;
        float mval = mask2[y*HW + x];
        float fire = (mval < 0.5f) ? 1.f : 0.f;
        const int pc = ((wv+1)*S1XP + (px+1))*CP;
        float* ob = dst + b*CHIMG + y*HW + x;

        f32x2 ra = *(const f32x2*)&st1[pc + 4*g];
        f32x2 rb = *(const f32x2*)&st1[pc + 4*g + 2];
        f32x2 t0 = {d0[0], d0[1]}, t1 = {d0[2], d0[3]};
        f32x2 o0 = ra + (t0 + b2p0) * fire;
        f32x2 o1 = rb + (t1 + b2p1) * fire;
        ob[(4*g + 0)*IMG] = o0.x;
        ob[(4*g + 1)*IMG] = o0.y;
        ob[(4*g + 2)*IMG] = o1.x;
        ob[(4*g + 3)*IMG] = o1.y;
        if (g < 2) {
            f32x2 rc = *(const f32x2*)&st1[pc + 16 + 4*g];
            f32x2 rd = *(const f32x2*)&st1[pc + 16 + 4*g + 2];
            f32x2 t2 = {d1[0], d1[1]}, t3 = {d1[2], d1[3]};
            f32x2 o2 = rc + (t2 + b2p2) * fire;
            f32x2 o3 = rd + (t3 + b2p3) * fire;
            ob[(16 + 4*g + 0)*IMG] = o2.x;
            ob[(16 + 4*g + 1)*IMG] = o2.y;
            ob[(16 + 4*g + 2)*IMG] = o3.x;
            ob[(16 + 4*g + 3)*IMG] = o3.y;
        }
    }
}

extern "C" void kernel_launch(void* const* d_in, const int* in_sizes, int n_in,
                              void* d_out, int out_size, void* d_ws, size_t ws_size,
                              hipStream_t stream) {
    const float* state = (const float*)d_in[0];
    const float* w1    = (const float*)d_in[1];
    const float* b1    = (const float*)d_in[2];
    const float* w2    = (const float*)d_in[3];
    const float* b2    = (const float*)d_in[4];
    const float* masks = (const float*)d_in[5];

    float* out = (float*)d_out;
    float* ws  = (float*)d_ws;
    const char* wsc = (const char*)d_ws;

    nca_pack_weights<<<dim3(1), dim3(256), 0, stream>>>(w1, b1, w2, b2, (char*)d_ws);

    // 16 fused launches, each advancing 2 steps. Launch i: steps 2i, 2i+1.
    for (int i = 0; i < 16; ++i) {
        const float* src = (i == 0) ? state : ((i & 1) ? ws : out);
        float*       dst = (i & 1) ? out : ws;
        nca_step2<<<dim3(512), dim3(512), 0, stream>>>(src, dst, wsc, masks, 2*i);
    }
}

// Round 11
// 173.713 us; speedup vs baseline: 1.6296x; 1.0089x over previous
//
#include <hip/hip_runtime.h>

typedef __bf16 bf16x8 __attribute__((ext_vector_type(8)));
typedef float  f32x4  __attribute__((ext_vector_type(4)));
typedef float  f32x2  __attribute__((ext_vector_type(2)));

#define NCH 24
#define CP  26        // padded channel stride (floats) -> conflict-free, 8B-aligned pairs
#define HW 128
#define IMG (HW*HW)
#define CHIMG (NCH*IMG)
#define SXP 20        // staged x (16 + 2*2 halo)
#define SYP 12        // staged y (8 + 2*2 halo)
#define S1XP 18       // step-1 intermediate x
#define S1YP 10       // step-1 intermediate y
#define S1N (S1XP*S1YP)   // 180
#define NW 8          // waves per block

// d_ws layout: [ping state: 4*CHIMG floats][w1 frags][w2 frags][b2 frags]
#define PW1_OFF ((size_t)(4*CHIMG)*4)
#define PW2_OFF (PW1_OFF + 12*64*8*2)
#define PB2_OFF (PW2_OFF + 4*64*8*2)

// One-time weight packing into MFMA A-fragment layout (bias-1 trick in t=3 slot).
// mfma_f32_16x16x32_bf16: A[row=l%16][k=8*(l/16)+j], B[k][col=l%16], D[row=4*(l/16)+r][col=l%16]
__global__ void nca_pack_weights(const float* __restrict__ w1, const float* __restrict__ b1,
                                 const float* __restrict__ w2, const float* __restrict__ b2,
                                 char* __restrict__ ws)
{
    short* pw1 = (short*)(ws + PW1_OFF);
    short* pw2 = (short*)(ws + PW2_OFF);
    float* pb2 = (float*)(ws + PB2_OFF);
    const int tid = threadIdx.x;
    for (int idx = tid; idx < 12*64*8; idx += 256) {
        int j  = idx & 7;
        int ll = (idx >> 3) & 63;
        int fs = idx >> 9;                  // m*3+s
        int m  = fs / 3, s = fs - 3*m;
        int row = m*16 + (ll & 15);         // h
        int kp  = 32*s + 8*(ll >> 4) + j;   // k' = 4c+t
        int c = kp >> 2, tt = kp & 3;
        float v;
        if (tt < 3) v = w1[row*72 + 3*c + tt];
        else        v = (c == 0) ? b1[row] : 0.f;
        pw1[idx] = (short)__builtin_bit_cast(unsigned short, (__bf16)v);
    }
    for (int idx = tid; idx < 4*64*8; idx += 256) {
        int j  = idx & 7;
        int ll = (idx >> 3) & 63;
        int fs = idx >> 9;                  // m2*2+s2
        int m2 = fs >> 1, s2 = fs & 1;
        int row = m2*16 + (ll & 15);        // o
        int h   = 32*s2 + 8*(ll >> 4) + j;
        float v = (row < 24) ? w2[row*64 + h] : 0.f;
        pw2[idx] = (short)__builtin_bit_cast(unsigned short, (__bf16)v);
    }
    for (int idx = tid; idx < 2*64*4; idx += 256) {
        int r  = idx & 3;
        int ll = (idx >> 2) & 63;
        int m2 = idx >> 8;
        int o  = m2*16 + 4*(ll >> 4) + r;
        pb2[idx] = (o < 24) ? b2[o] : 0.f;
    }
}

// One NCA micro-step for one pixel-slot: perception (packed-f32 channel-pair
// math from a pixel-major LDS tile) -> GEMM1 (w1 frags in VGPRs) -> relu/
// transpose (per-wave Hb) -> GEMM2 (w2 frags from LDS).
template<int XP>
__device__ __forceinline__ void nca_mlp(
    const float* __restrict__ stsrc, int sy, int sx,
    int l, int px, int g, short (*hbw)[72],
    const bf16x8 (&w1r)[12], const short* __restrict__ w2l,
    f32x4& d0, f32x4& d1)
{
    const float* base = stsrc + ((sy-1)*XP + (sx-1))*CP + 2*g;
    bf16x8 pf[3];
    #pragma unroll
    for (int s = 0; s < 3; ++s) {
        #define LDV(dy,dx) (*(const f32x2*)(base + ((dy)*XP + (dx))*CP + 8*s))
        f32x2 v00=LDV(0,0), v01=LDV(0,1), v02=LDV(0,2);
        f32x2 v10=LDV(1,0), v11=LDV(1,1), v12=LDV(1,2);
        f32x2 v20=LDV(2,0), v21=LDV(2,1), v22=LDV(2,2);
        #undef LDV
        f32x2 gx = (v02 - v00 + 2.f*(v12 - v10) + (v22 - v20)) * 0.125f;
        f32x2 gy = (v20 - v00 + 2.f*(v21 - v01) + (v22 - v02)) * 0.125f;
        pf[s][0] = (__bf16)v11.x;
        pf[s][1] = (__bf16)gx.x;
        pf[s][2] = (__bf16)gy.x;
        pf[s][3] = (__bf16)((s == 0 && g == 0) ? 1.f : 0.f);   // bias-1 slot (c==0)
        pf[s][4] = (__bf16)v11.y;
        pf[s][5] = (__bf16)gx.y;
        pf[s][6] = (__bf16)gy.y;
        pf[s][7] = (__bf16)0.f;
    }

    // GEMM1: H^T = w1' x p~^T  (A-frags live in VGPRs -- no loads)
    f32x4 acc1[4] = {};
    __builtin_amdgcn_s_setprio(1);
    #pragma unroll
    for (int m = 0; m < 4; ++m) {
        #pragma unroll
        for (int s = 0; s < 3; ++s) {
            acc1[m] = __builtin_amdgcn_mfma_f32_16x16x32_bf16(w1r[m*3 + s], pf[s], acc1[m], 0, 0, 0);
        }
    }
    __builtin_amdgcn_s_setprio(0);

    // relu + per-wave transpose: 4 shorts (rows h0..h0+3) per 8B write
    #pragma unroll
    for (int m = 0; m < 4; ++m) {
        unsigned int b0 = __builtin_bit_cast(unsigned short, (__bf16)fmaxf(acc1[m][0], 0.f));
        unsigned int b1_ = __builtin_bit_cast(unsigned short, (__bf16)fmaxf(acc1[m][1], 0.f));
        unsigned int b2_ = __builtin_bit_cast(unsigned short, (__bf16)fmaxf(acc1[m][2], 0.f));
        unsigned int b3 = __builtin_bit_cast(unsigned short, (__bf16)fmaxf(acc1[m][3], 0.f));
        uint2 w; w.x = b0 | (b1_ << 16); w.y = b2_ | (b3 << 16);
        *(uint2*)&hbw[px][m*16 + 4*g] = w;      // 8B-aligned
    }
    // same-wave write->read: compiler inserts lgkmcnt wait, no barrier needed

    // GEMM2: delta^T = w2 x relu(H)^T  (A-frags from LDS, base+imm offsets)
    f32x4 acc2[2] = {};
    #pragma unroll
    for (int s2 = 0; s2 < 2; ++s2) {
        bf16x8 hv = *(const bf16x8*)&hbw[px][8*g + 32*s2];
        __builtin_amdgcn_s_setprio(1);
        #pragma unroll
        for (int m2 = 0; m2 < 2; ++m2) {
            bf16x8 a2 = *(const bf16x8*)&w2l[((m2*2 + s2)*64 + l)*8];
            acc2[m2] = __builtin_amdgcn_mfma_f32_16x16x32_bf16(a2, hv, acc2[m2], 0, 0, 0);
        }
        __builtin_amdgcn_s_setprio(0);
    }
    d0 = acc2[0];
    d1 = acc2[1];
}

// Fused 2-step NCA (temporal blocking, halo=2), 16x8 output tile, 8 waves,
// pixel-major LDS tiles, w1 frags in VGPRs, w2 frags + fire masks in LDS.
__global__ __launch_bounds__(512, 4) void nca_step2(
    const float* __restrict__ src, float* __restrict__ dst,
    const char* __restrict__ wsp, const float* __restrict__ masks, int step0)
{
    __shared__ __align__(16) float st_in[SYP*SXP*CP];   // 24960 B, [y][x][c]
    __shared__ __align__(16) float st1[S1YP*S1XP*CP];   // 18720 B
    __shared__ __align__(16) short Hb[NW][16][72];      // 18432 B
    __shared__ __align__(16) short w2l[4*64*8];         //  4096 B
    __shared__ __align__(16) float fire1[S1N];          //   720 B (10x18)
    __shared__ __align__(16) float fire2[128];          //   512 B (8x16)

    const short* __restrict__ pw1 = (const short*)(wsp + PW1_OFF);
    const float* __restrict__ pb2 = (const float*)(wsp + PB2_OFF);

    const int tid = threadIdx.x;
    const int wv  = tid >> 6;          // 0..7
    const int l   = tid & 63;
    const int px  = l & 15;
    const int g   = l >> 4;

    // ---- hoist w1 A-fragments into VGPRs (once per launch, 48 VGPR) ----
    bf16x8 w1r[12];
    #pragma unroll
    for (int i = 0; i < 12; ++i)
        w1r[i] = *(const bf16x8*)&pw1[(i*64 + l)*8];

    // XCD-contiguous tile mapping: XCD k (bid%8) owns tiles [64k, 64k+64)
    // = half a batch image -> ping-pong state slab stays in that XCD's L2.
    const int bid = blockIdx.x;
    const int t   = (bid & 7) * 64 + (bid >> 3);   // 512 blocks, bijective
    const int b   = t >> 7;                        // batch (128 tiles each)
    const int rem = t & 127;
    const int y0  = (rem >> 3) * 8;                // 16 y-tiles
    const int x0  = (rem & 7) * 16;                // 8 x-tiles

    // ---- copy w2 fragments into LDS (once per launch, 4 KB) ----
    if (tid < 256) {
        ((uint4*)w2l)[tid] = ((const uint4*)(wsp + PW2_OFF))[tid];
    }

    // ---- stage fire masks (precomputed (m < 0.5) && in-image, as 0/1 f32) ----
    const float* mask1 = masks + ((size_t)step0*4 + b)*IMG;
    const float* mask2 = masks + ((size_t)(step0+1)*4 + b)*IMG;
    if (tid < S1N) {                       // 180 threads: 10x18 region of step-A outputs
        int r1 = tid / S1XP;
        int c1 = tid - r1*S1XP;
        int gy = y0 + r1 - 1;
        int gx = x0 + c1 - 1;
        float f = 0.f;
        if ((unsigned)gy < (unsigned)HW && (unsigned)gx < (unsigned)HW)
            f = (mask1[gy*HW + gx] < 0.5f) ? 1.f : 0.f;
        fire1[tid] = f;
    } else if (tid >= 256 && tid < 384) {  // 128 threads: 8x16 core for step B
        int q = tid - 256;
        int y = y0 + (q >> 4);
        int x = x0 + (q & 15);
        fire2[q] = (mask2[y*HW + x] < 0.5f) ? 1.f : 0.f;
    }

    // ---- stage 12x20 state tile, pixel-major, strength-reduced addressing ----
    const float* sb = src + b * CHIMG;
    if (tid < 480) {
        const int c  = tid / 20;          // 0..23
        const int x  = tid - c*20;        // 0..19
        const int gx = x0 + x - 2;
        const bool vx = (unsigned)gx < (unsigned)HW;
        const float* gp = sb + c*IMG + (y0 - 2)*HW + gx;
        float* lp = &st_in[x*CP + c];
        int gy = y0 - 2;
        #pragma unroll
        for (int yy = 0; yy < SYP; ++yy) {
            bool v = vx && ((unsigned)gy < (unsigned)HW);
            lp[yy*SXP*CP] = v ? gp[yy*HW] : 0.f;
            ++gy;
        }
    }
    __syncthreads();

    f32x4 b2v0 = *(const f32x4*)&pb2[(0*64 + l)*4];
    f32x4 b2v1 = *(const f32x4*)&pb2[(1*64 + l)*4];
    const f32x2 b2p0 = {b2v0[0], b2v0[1]}, b2p1 = {b2v0[2], b2v0[3]};
    const f32x2 b2p2 = {b2v1[0], b2v1[1]}, b2p3 = {b2v1[2], b2v1[3]};

    // ============ STEP A: 180 px (10x18) in 12 slots of 16 ============
    #pragma unroll
    for (int it = 0; it < 2; ++it) {
        const int slot = it*NW + wv;
        if (slot < 12) {                           // wave-uniform predicate
            const int q  = slot*16 + px;
            const bool lane_valid = (q < S1N);
            const int qq = lane_valid ? q : 0;
            const int r1 = qq / S1XP;
            const int c1 = qq - r1*S1XP;

            f32x4 d0, d1;
            nca_mlp<SXP>(st_in, r1+1, c1+1, l, px, g, Hb[wv], w1r, w2l, d0, d1);

            // epilogue into st1: OOB px auto-zero (st_in pad=0, fire=0)
            float fire = fire1[qq];
            if (lane_valid) {
                const int pc = ((r1+1)*SXP + (c1+1))*CP;   // st_in center pixel
                const int pd = (r1*S1XP + c1)*CP;          // st1 pixel
                f32x2 ra = *(const f32x2*)&st_in[pc + 4*g];
                f32x2 rb = *(const f32x2*)&st_in[pc + 4*g + 2];
                f32x2 t0 = {d0[0], d0[1]}, t1 = {d0[2], d0[3]};
                *(f32x2*)&st1[pd + 4*g]     = ra + (t0 + b2p0) * fire;
                *(f32x2*)&st1[pd + 4*g + 2] = rb + (t1 + b2p1) * fire;
                if (g < 2) {
                    f32x2 rc = *(const f32x2*)&st_in[pc + 16 + 4*g];
                    f32x2 rd = *(const f32x2*)&st_in[pc + 16 + 4*g + 2];
                    f32x2 t2 = {d1[0], d1[1]}, t3 = {d1[2], d1[3]};
                    *(f32x2*)&st1[pd + 16 + 4*g]     = rc + (t2 + b2p2) * fire;
                    *(f32x2*)&st1[pd + 16 + 4*g + 2] = rd + (t3 + b2p3) * fire;
                }
            }
        }
    }
    __syncthreads();   // all step-A writes visible before step-B reads

    // ============ STEP B: 8x16 core, wave wv = output row y0+wv ============
    {
        f32x4 d0, d1;
        nca_mlp<S1XP>(st1, wv+1, px+1, l, px, g, Hb[wv], w1r, w2l, d0, d1);

        const int x = x0 + px;
        const int y = y0 + wv;
        float fire = fire2[wv*16 + px];
        const int pc = ((wv+1)*S1XP + (px+1))*CP;
        float* ob = dst + b*CHIMG + y*HW + x;

        f32x2 ra = *(const f32x2*)&st1[pc + 4*g];
        f32x2 rb = *(const f32x2*)&st1[pc + 4*g + 2];
        f32x2 t0 = {d0[0], d0[1]}, t1 = {d0[2], d0[3]};
        f32x2 o0 = ra + (t0 + b2p0) * fire;
        f32x2 o1 = rb + (t1 + b2p1) * fire;
        ob[(4*g + 0)*IMG] = o0.x;
        ob[(4*g + 1)*IMG] = o0.y;
        ob[(4*g + 2)*IMG] = o1.x;
        ob[(4*g + 3)*IMG] = o1.y;
        if (g < 2) {
            f32x2 rc = *(const f32x2*)&st1[pc + 16 + 4*g];
            f32x2 rd = *(const f32x2*)&st1[pc + 16 + 4*g + 2];
            f32x2 t2 = {d1[0], d1[1]}, t3 = {d1[2], d1[3]};
            f32x2 o2 = rc + (t2 + b2p2) * fire;
            f32x2 o3 = rd + (t3 + b2p3) * fire;
            ob[(16 + 4*g + 0)*IMG] = o2.x;
            ob[(16 + 4*g + 1)*IMG] = o2.y;
            ob[(16 + 4*g + 2)*IMG] = o3.x;
            ob[(16 + 4*g + 3)*IMG] = o3.y;
        }
    }
}

extern "C" void kernel_launch(void* const* d_in, const int* in_sizes, int n_in,
                              void* d_out, int out_size, void* d_ws, size_t ws_size,
                              hipStream_t stream) {
    const float* state = (const float*)d_in[0];
    const float* w1    = (const float*)d_in[1];
    const float* b1    = (const float*)d_in[2];
    const float* w2    = (const float*)d_in[3];
    const float* b2    = (const float*)d_in[4];
    const float* masks = (const float*)d_in[5];

    float* out = (float*)d_out;
    float* ws  = (float*)d_ws;
    const char* wsc = (const char*)d_ws;

    nca_pack_weights<<<dim3(1), dim3(256), 0, stream>>>(w1, b1, w2, b2, (char*)d_ws);

    // 16 fused launches, each advancing 2 steps. Launch i: steps 2i, 2i+1.
    for (int i = 0; i < 16; ++i) {
        const float* src = (i == 0) ? state : ((i & 1) ? ws : out);
        float*       dst = (i & 1) ? out : ws;
        nca_step2<<<dim3(512), dim3(512), 0, stream>>>(src, dst, wsc, masks, 2*i);
    }
}